// Round 4
// baseline (12.443 us; speedup 1.0000x reference)
//
#include <hip/hip_runtime.h>

// QuanvolutionClassifier, closed form.
//
// Derivation: RY(x)|0> = [cos(x/2), sin(x/2)]. RZ phases are unit-modulus and
// CNOT(0,1)/CNOT(2,3) merely permute computational-basis indices
// (j -> j^i, l -> l^k), so |amplitude|^2 after the circuit is
//   P[i,j,k,l] = q0[i]^2 * q1[j^i]^2 * q2[k]^2 * q3[l^k]^2   (theta drops out).
// Hence  <Z0>=cos(a), <Z1>=cos(a)cos(b), <Z2>=cos(c), <Z3>=cos(c)cos(d)
// for the 2x2 patch [a b; c d]. Then logits = feats @ W^T + bias, log_softmax.
//
// R4: 16 rows/block (1024 thr, 256 blocks = 1/CU) -> W staging traffic
// 32MB -> 8MB and one barrier per 16 rows. Feature computation (x loads +
// cos) hoisted ABOVE the barrier so x-load latency overlaps the W staging
// drain. Post-barrier phase is pure ds_read_b128 (immediate offsets) + FMA.

typedef float f32x2 __attribute__((ext_vector_type(2)));

__global__ __launch_bounds__(1024, 4) void quanv_fused(
    const float* __restrict__ x,     // [B, 784]
    const float* __restrict__ W,     // [10, 784]
    const float* __restrict__ bias,  // [10]
    float* __restrict__ out,         // [B, 10]
    int B)
{
    __shared__ float Wl[7840];       // [10][784]
    __shared__ float bl[10];

    const int tid  = threadIdx.x;
    const int wv   = tid >> 6;                 // wave in block: 0..15
    const int lane = tid & 63;
    const int row  = (blockIdx.x << 4) + wv;   // one wave per batch row
    const bool rowok = row < B;

    // ---- stage W into LDS: 1960 float4 over 1024 threads (<=2 each) ----
    {
        const float4* __restrict__ Wg4 = reinterpret_cast<const float4*>(W);
        float4* Wl4 = reinterpret_cast<float4*>(Wl);
        const float4 s0 = Wg4[tid];
        Wl4[tid] = s0;
        if (tid < 936) {                       // 1960 - 1024
            const float4 s1 = Wg4[tid + 1024];
            Wl4[tid + 1024] = s1;
        }
        if (tid < 10) bl[tid] = bias[tid];
    }

    // ---- pre-barrier: compute features (depends only on x) so the x-load
    //      latency + transcendentals overlap with the W staging drain ----
    float f[16];
    const f32x2* __restrict__ xr2 =
        reinterpret_cast<const f32x2*>(x + (size_t)row * 784);
#pragma unroll
    for (int it = 0; it < 4; ++it) {
        const int p = lane + (it << 6);
        if (rowok && p < 196) {
            const int pr = p / 14;
            const int pc = p - pr * 14;
            const int t2 = pr * 28 + pc;       // float2 index of top pair
            const f32x2 top = __builtin_nontemporal_load(&xr2[t2]);
            const f32x2 bot = __builtin_nontemporal_load(&xr2[t2 + 14]);
            f[it * 4 + 0] = __cosf(top.x);
            f[it * 4 + 1] = f[it * 4 + 0] * __cosf(top.y);
            f[it * 4 + 2] = __cosf(bot.x);
            f[it * 4 + 3] = f[it * 4 + 2] * __cosf(bot.y);
        }
    }

    __syncthreads();

    if (!rowok) return;

    // ---- post-barrier: pure LDS reads + FMA ----
    float acc[10];
#pragma unroll
    for (int c = 0; c < 10; ++c) acc[c] = 0.0f;

    const float* __restrict__ wl = Wl + (lane << 2);   // &Wl[lane*4]
#pragma unroll
    for (int it = 0; it < 4; ++it) {
        const int p = lane + (it << 6);
        if (p < 196) {                         // branch-free for it<3
#pragma unroll
            for (int c = 0; c < 10; ++c) {
                // ds_read_b128, immediate offset = it*1024 + c*3136 bytes
                const float4 w = *reinterpret_cast<const float4*>(
                    wl + (it << 8) + c * 784);
                acc[c] = fmaf(f[it * 4 + 0], w.x,
                         fmaf(f[it * 4 + 1], w.y,
                         fmaf(f[it * 4 + 2], w.z,
                         fmaf(f[it * 4 + 3], w.w, acc[c]))));
            }
        }
    }

    // butterfly reduce the 10 class partials across the wave (64 lanes)
#pragma unroll
    for (int off = 32; off > 0; off >>= 1) {
#pragma unroll
        for (int c = 0; c < 10; ++c)
            acc[c] += __shfl_xor(acc[c], off, 64);
    }

    if (lane == 0) {
        float m = -3.4e38f;
#pragma unroll
        for (int c = 0; c < 10; ++c) {
            acc[c] += bl[c];
            m = fmaxf(m, acc[c]);
        }
        float s = 0.0f;
#pragma unroll
        for (int c = 0; c < 10; ++c) s += __expf(acc[c] - m);
        const float lse = m + __logf(s);
        f32x2* __restrict__ o2 =
            reinterpret_cast<f32x2*>(out + (size_t)row * 10);  // 8B-aligned
#pragma unroll
        for (int k = 0; k < 5; ++k) {
            f32x2 v;
            v.x = acc[2 * k] - lse;
            v.y = acc[2 * k + 1] - lse;
            o2[k] = v;
        }
    }
}

extern "C" void kernel_launch(void* const* d_in, const int* in_sizes, int n_in,
                              void* d_out, int out_size, void* d_ws, size_t ws_size,
                              hipStream_t stream) {
    const float* x   = (const float*)d_in[0];
    // d_in[1] = theta: provably unused (RZ phases cancel in |amp|^2 after CNOT
    // basis permutation — see derivation above).
    const float* W   = (const float*)d_in[2];
    const float* b   = (const float*)d_in[3];
    float* out       = (float*)d_out;

    const int B = in_sizes[0] / 784;
    const int blocks = (B + 15) / 16;   // 16 rows (waves) per block
    quanv_fused<<<blocks, 1024, 0, stream>>>(x, W, b, out, B);
}

// Round 5
// 9.724 us; speedup vs baseline: 1.2796x; 1.2796x over previous
//
#include <hip/hip_runtime.h>

// QuanvolutionClassifier, closed form + MFMA.
//
// Circuit collapses analytically (theta drops out; see prior rounds):
//   feats per 2x2 patch [a b; c d] = {cos a, cos a cos b, cos c, cos c cos d}
//   out = log_softmax(feats @ W^T + bias)
//
// R5: the dot+reduce was LDS-pipe-bound (40 conflicted ds_read_b128 + 60
// shuffles per row). Replace with mfma_f32_16x16x32_bf16:
//   A-frag: lane holds row (lane&15), k = (lane>>4)*8 + j  -> 8 feats =
//           exactly 2 whole patches (patch idx 8t+2h is always even), so
//           features are built in registers from two float4 x-loads.
//   B-frag: lane holds col (lane&15) = class, contiguous k -> one
//           ds_read_b128 from W staged bf16 in LDS [16][800], zero-padded.
//   C-frag: col = lane&15, row = (lane>>4)*4 + reg   [m89-verified mapping]
// 8 waves split the 25 k-steps (K=784 -> 800 padded); partials summed in LDS.

typedef float f32x4 __attribute__((ext_vector_type(4)));
typedef short s16x8 __attribute__((ext_vector_type(8)));

__device__ __forceinline__ ushort f2bf(float f) {   // f32 -> bf16 RNE
    unsigned u = __float_as_uint(f);
    u += 0x7fffu + ((u >> 16) & 1u);
    return (ushort)(u >> 16);
}

__global__ __launch_bounds__(512, 2) void quanv_mfma(
    const float* __restrict__ x,     // [B, 784]
    const float* __restrict__ W,     // [10, 784]
    const float* __restrict__ bias,  // [10]
    float* __restrict__ out,         // [B, 10]
    int B)
{
    __shared__ __align__(16) ushort Wb[16][800];  // bf16 W, zero-padded
    __shared__ float Cp[8][16][16];               // per-wave C partials
    __shared__ float bl[16];

    const int tid  = threadIdx.x;
    const int wv   = tid >> 6;          // wave 0..7  (k-split)
    const int lane = tid & 63;
    const int h    = lane >> 4;         // k-subgroup 0..3
    const int col  = lane & 15;         // A: row-in-tile / B: class column
    const int rbase = blockIdx.x << 4;  // 16 batch rows per block

    // ---- stage W -> bf16 LDS, zero-padded to [16][800], single pass ----
    {
        const float4* __restrict__ W4 = reinterpret_cast<const float4*>(W);
        for (int i4 = tid; i4 < 3200; i4 += 512) {   // 16*800/4
            const int c  = i4 / 200;
            const int k4 = i4 - c * 200;
            ushort4 v = {0, 0, 0, 0};
            if (c < 10 && k4 < 196) {
                const float4 wq = W4[c * 196 + k4];
                v.x = f2bf(wq.x); v.y = f2bf(wq.y);
                v.z = f2bf(wq.z); v.w = f2bf(wq.w);
            }
            *reinterpret_cast<ushort4*>(&Wb[c][k4 << 2]) = v;
        }
        if (tid < 10) bl[tid] = bias[tid];
        if (tid >= 10 && tid < 16) bl[tid] = 0.0f;
    }

    // row this lane computes features for (A-frag row = lane&15)
    int r = rbase + col;
    if (r >= B) r = B - 1;
    const float* __restrict__ xr = x + (size_t)r * 784;

    __syncthreads();

    // ---- main loop: 25 k-steps of 32, split across 8 waves ----
    f32x4 acc = {0.f, 0.f, 0.f, 0.f};
    for (int t = wv; t < 25; t += 8) {
        const int p0 = 8 * t + 2 * h;          // first of lane's 2 patches
        const bool ok = p0 < 196;              // k >= 784 tail (t=24, h>=2)
        const int pp = ok ? p0 : 0;
        const int pr = pp / 14;                // pp even -> pc even <= 12
        const int pc = pp - pr * 14;
        const float4* __restrict__ xp =
            reinterpret_cast<const float4*>(xr + pr * 56 + 2 * pc);
        const float4 top = xp[0];              // img row 2pr, cols 2pc..+3
        const float4 bot = xp[7];              // img row 2pr+1 (+28 floats)
        float f0 = __cosf(top.x), f1 = f0 * __cosf(top.y);
        float f2 = __cosf(bot.x), f3 = f2 * __cosf(bot.y);
        float f4 = __cosf(top.z), f5 = f4 * __cosf(top.w);
        float f6 = __cosf(bot.z), f7 = f6 * __cosf(bot.w);
        if (!ok) { f0=f1=f2=f3=f4=f5=f6=f7=0.f; }
        s16x8 a = { (short)f2bf(f0), (short)f2bf(f1),
                    (short)f2bf(f2), (short)f2bf(f3),
                    (short)f2bf(f4), (short)f2bf(f5),
                    (short)f2bf(f6), (short)f2bf(f7) };
        const s16x8 b = *reinterpret_cast<const s16x8*>(
            &Wb[col][32 * t + (h << 3)]);      // contiguous k, 16B aligned
        acc = __builtin_amdgcn_mfma_f32_16x16x32_bf16(a, b, acc, 0, 0, 0);
    }

    // ---- per-wave partials -> LDS ----
#pragma unroll
    for (int j = 0; j < 4; ++j)
        Cp[wv][(h << 2) + j][col] = acc[j];    // C row = (lane>>4)*4 + j

    __syncthreads();

    // ---- epilogue: one thread per batch row ----
    if (tid < 16) {
        const int rr = rbase + tid;
        if (rr < B) {
            float s[10];
#pragma unroll
            for (int c = 0; c < 10; ++c) s[c] = bl[c];
#pragma unroll
            for (int w = 0; w < 8; ++w)
#pragma unroll
                for (int c = 0; c < 10; ++c) s[c] += Cp[w][tid][c];
            float m = s[0];
#pragma unroll
            for (int c = 1; c < 10; ++c) m = fmaxf(m, s[c]);
            float sum = 0.f;
#pragma unroll
            for (int c = 0; c < 10; ++c) sum += __expf(s[c] - m);
            const float lse = m + __logf(sum);
            float* __restrict__ o = out + (size_t)rr * 10;
#pragma unroll
            for (int c = 0; c < 10; ++c) o[c] = s[c] - lse;
        }
    }
}

extern "C" void kernel_launch(void* const* d_in, const int* in_sizes, int n_in,
                              void* d_out, int out_size, void* d_ws, size_t ws_size,
                              hipStream_t stream) {
    const float* x   = (const float*)d_in[0];
    // d_in[1] = theta: provably unused (RZ phases cancel in |amp|^2).
    const float* W   = (const float*)d_in[2];
    const float* b   = (const float*)d_in[3];
    float* out       = (float*)d_out;

    const int B = in_sizes[0] / 784;
    const int blocks = (B + 15) / 16;     // 16 rows per block -> 256 blocks
    quanv_mfma<<<blocks, 512, 0, stream>>>(x, W, b, out, B);
}